// Round 8
// baseline (273.193 us; speedup 1.0000x reference)
//
#include <hip/hip_runtime.h>
#include <hip/hip_bf16.h>

#define TPB 256

typedef __attribute__((ext_vector_type(8))) short short8v;   // 8 bf16 (4 VGPRs) MFMA operand
typedef __attribute__((ext_vector_type(4))) float f32x4;     // MFMA accumulator

__device__ __forceinline__ float bf2f(unsigned int u) {
    return __uint_as_float(u << 16);
}
// v_cvt_pk_bf16_f32: lo=bf16(x), hi=bf16(y), RNE, single VALU op.
__device__ __forceinline__ unsigned int packbf(float x, float y) {
    unsigned int r;
    asm("v_cvt_pk_bf16_f32 %0, %1, %2" : "=v"(r) : "v"(x), "v"(y));
    return r;
}
__device__ __forceinline__ short8v pack8(float4 a, float4 bq) {
    union { unsigned int u[4]; short8v s; } c;
    c.u[0] = packbf(a.x, a.y);  c.u[1] = packbf(a.z, a.w);
    c.u[2] = packbf(bq.x, bq.y); c.u[3] = packbf(bq.z, bq.w);
    return c.s;
}

// One block per image, 4 waves, 16 strips of 64 px (2 image rows).
// ROLLING state window [16ch][8 rows][36] bf16 (rows live: 2s-1..2s+6) and
// rolling alpha [9][34] (slot 8 = permanent zero) -> 38.1 KB LDS -> 4 blocks/CU.
// Wave-private sP/sH rows -> 1 barrier/strip; gating deferred 2 strips.
__global__ __launch_bounds__(TPB, 4) void nca_mfma(
    const float* __restrict__ state,   // [B,16,32,32]
    const int*   __restrict__ rmask,   // [B,1,32,32]
    const float* __restrict__ w1,      // [128,48]
    const float* __restrict__ b1,      // [128]
    const float* __restrict__ w2,      // [16,128]
    const float* __restrict__ b2,      // [16]
    float* __restrict__ out)           // [B,16,32,32]
{
    __shared__ __align__(16) unsigned short sSt[16 * 8 * 36]; // rolling bf16 state; ch*288 + (row&7)*36 + imgcol+2
    __shared__ __align__(16) unsigned short sP [64 * 72];      // perception, stride 72 shorts; wave-private rows
    __shared__ __align__(16) unsigned short sH [64 * 136];     // hidden bf16, stride 136; wave-private rows
    __shared__ __align__(16) float          sA [9 * 34];       // rolling new-alpha; (row&7)*34 + imgcol+1; slot 8 = zero
    __shared__ unsigned char                sPre[1024];        // pre-state alive pool (filled strip by strip)

    const int b    = blockIdx.x;
    const int tid  = threadIdx.x;
    const int lane = tid & 63;
    const int wv   = tid >> 6;     // wave 0..3
    const int lr   = lane & 15;
    const int lg   = lane >> 4;    // 0..3

    // ---------------- weight fragments (registers) ----------------
    short8v w1f[8][2];
    short8v w2f[4];
    float   b1v[8];
    #pragma unroll
    for (int n = 0; n < 8; ++n) {
        const int f = lr * 8 + n;
        #pragma unroll
        for (int kk = 0; kk < 2; ++kk) {
            const int k0 = kk * 32 + lg * 8;
            if (k0 < 48) {
                const float4 x0 = *reinterpret_cast<const float4*>(w1 + f * 48 + k0);
                const float4 x1 = *reinterpret_cast<const float4*>(w1 + f * 48 + k0 + 4);
                w1f[n][kk] = pack8(x0, x1);
            } else {
                short8v z = {0,0,0,0,0,0,0,0};
                w1f[n][kk] = z;
            }
        }
        b1v[n] = b1[f];
    }
    #pragma unroll
    for (int ks = 0; ks < 4; ++ks) {
        const int k0 = ks * 32 + lg * 8;
        const float4 x0 = *reinterpret_cast<const float4*>(w2 + lr * 128 + k0);
        const float4 x1 = *reinterpret_cast<const float4*>(w2 + lr * 128 + k0 + 4);
        w2f[ks] = pack8(x0, x1);
    }
    const float b2v = b2[lr];

    // ---------------- zero LDS (halo cols/slots, sA, sP K-pad) ----------------
    for (int i = tid; i < 16*8*36/2; i += TPB) reinterpret_cast<unsigned int*>(sSt)[i] = 0u;
    for (int i = tid; i < 64*72/2;   i += TPB) reinterpret_cast<unsigned int*>(sP)[i]  = 0u;
    for (int i = tid; i < 9*34;      i += TPB) sA[i] = 0.f;
    __syncthreads();

    // ---------------- prologue: stage image rows 0..4 (slots 0..4) ----------------
    const float* gs = state + (size_t)b * 16384;
    #pragma unroll
    for (int k = 0; k < 3; ++k) {
        const int q = tid + k * TPB;            // 0..639 float4s (5 rows x 16 ch x 8)
        if (q < 640) {
            const int ch = q / 40, rem = q - ch * 40;
            const int row = rem >> 3, px4 = rem & 7;
            const float4 v = reinterpret_cast<const float4*>(gs)[ch * 256 + row * 8 + px4];
            unsigned int* dst = reinterpret_cast<unsigned int*>(&sSt[ch * 288 + row * 36 + px4 * 4 + 2]);
            dst[0] = packbf(v.x, v.y);
            dst[1] = packbf(v.z, v.w);
        }
    }
    __syncthreads();

    // gate strip g (pixels g*64 + wv*16 .. +15, all in one image row)
    auto do_gate = [&](int g, const float* xp) {
        float av = 0.f;
        if (lane < 16) {
            const int p = g * 64 + wv * 16 + lane;
            const int h = p >> 5, w = p & 31;
            const int sm = (h - 1 >= 0) ? ((h - 1) & 7) : 8;
            const int s0 = h & 7;
            const int sp = (h + 1 <= 31) ? ((h + 1) & 7) : 8;
            const float* r0 = &sA[sm * 34 + w];   // cols w-1..w+1 -> idx w..w+2
            const float* r1 = &sA[s0 * 34 + w];
            const float* r2 = &sA[sp * 34 + w];
            float m =          r0[0];
            m = fmaxf(m, r0[1]); m = fmaxf(m, r0[2]);
            m = fmaxf(m, r1[0]); m = fmaxf(m, r1[1]); m = fmaxf(m, r1[2]);
            m = fmaxf(m, r2[0]); m = fmaxf(m, r2[1]); m = fmaxf(m, r2[2]);
            av = ((m > 0.1f) && (sPre[p] != 0)) ? 1.f : 0.f;
        }
        const float g0 = __shfl(av, lg * 4 + 0);
        const float g1 = __shfl(av, lg * 4 + 1);
        const float g2 = __shfl(av, lg * 4 + 2);
        const float g3 = __shfl(av, lg * 4 + 3);
        float4 ov;
        ov.x = g0 * fminf(fmaxf(xp[0], 0.f), 1.f);
        ov.y = g1 * fminf(fmaxf(xp[1], 0.f), 1.f);
        ov.z = g2 * fminf(fmaxf(xp[2], 0.f), 1.f);
        ov.w = g3 * fminf(fmaxf(xp[3], 0.f), 1.f);
        *reinterpret_cast<float4*>(&out[(size_t)b * 16384 + lr * 1024 + g * 64 + wv * 16 + lg * 4]) = ov;
    };

    float xq[2][4];    // 2-deep strip pipeline of this lane's outputs

    // prefetch roles (constant per thread)
    const int pf_ch  = tid >> 4;
    const int pf_rl  = (tid & 15) >> 3;
    const int pf_px4 = tid & 7;

    for (int s = 0; s < 16; ++s) {
        const int pbase = s * 64 + wv * 16;
        // residual-path inputs (consumed at [C])
        const int4   mi  = *reinterpret_cast<const int4*>(&rmask[b * 1024 + pbase + lg * 4]);
        const float4 idv = *reinterpret_cast<const float4*>(&state[(size_t)b * 16384 + lr * 1024 + pbase + lg * 4]);

        // issue prefetch of rows 2s+5, 2s+6 (needed first at strip s+2)
        const int pf_row = 2 * s + 5 + pf_rl;
        float4 pf = {0.f, 0.f, 0.f, 0.f};
        const bool pf_do = (pf_row <= 32);
        if (pf_row <= 31)
            pf = reinterpret_cast<const float4*>(gs)[pf_ch * 256 + pf_row * 8 + pf_px4];

        // ===== [A] perception for THIS WAVE's 16 px (2 px x 2 ch per lane) =====
        {
            const int cg   = lane & 7;        // channel pair
            const int pl   = lane >> 3;       // 0..7 pixel-pair within wave
            const int c0   = cg * 2;
            const int hloc = wv >> 1;         // 0/1
            const int w0   = (wv & 1) * 16 + pl * 2;   // even image col
            const int rr0  = 2 * s + hloc - 1;         // top image row of 3x3
            const int j0   = hloc * 32 + w0;  // strip-local px (even)
            float sx0[2], sx1[2], sy0[2], sy1[2], id0[2], id1[2];
            float mp0 = 0.f, mp1 = 0.f;       // ch-3 pre-alive maxes (only cg==1 uses)
            #pragma unroll
            for (int ci = 0; ci < 2; ++ci) {
                const unsigned short* bp = &sSt[(c0 + ci) * 288 + w0];
                float A[3], Bv[3], Cv[3], D[3];
                #pragma unroll
                for (int dr = 0; dr < 3; ++dr) {
                    const int slot = ((rr0 + dr) & 7) * 36;   // rows -1,32 land in zeroed slots
                    const unsigned int* rp = reinterpret_cast<const unsigned int*>(bp + slot);
                    const unsigned int u0 = rp[0], u1 = rp[1], u2 = rp[2];
                    A[dr]  = bf2f(u0 >> 16);        // image col w0-1
                    Bv[dr] = bf2f(u1 & 0xffffu);    // w0
                    Cv[dr] = bf2f(u1 >> 16);        // w0+1
                    D[dr]  = bf2f(u2 & 0xffffu);    // w0+2
                }
                const float csa = A[0]  + 2.f * A[1]  + A[2];
                const float csb = Bv[0] + 2.f * Bv[1] + Bv[2];
                const float csc = Cv[0] + 2.f * Cv[1] + Cv[2];
                const float csd = D[0]  + 2.f * D[1]  + D[2];
                sx0[ci] = csc - csa;
                sx1[ci] = csd - csb;
                sy0[ci] = (A[2] + 2.f * Bv[2] + Cv[2]) - (A[0] + 2.f * Bv[0] + Cv[0]);
                sy1[ci] = (Bv[2] + 2.f * Cv[2] + D[2]) - (Bv[0] + 2.f * Cv[0] + D[0]);
                id0[ci] = Bv[1];
                id1[ci] = Cv[1];
                if (ci == 1) {   // channel c0+1: for cg==1 this is alpha (ch 3)
                    #pragma unroll
                    for (int dr = 0; dr < 3; ++dr) {
                        mp0 = fmaxf(mp0, fmaxf(fmaxf(A[dr], Bv[dr]), Cv[dr]));
                        mp1 = fmaxf(mp1, fmaxf(fmaxf(Bv[dr], Cv[dr]), D[dr]));
                    }
                }
            }
            unsigned int* r0 = reinterpret_cast<unsigned int*>(&sP[j0 * 72 + c0]);
            unsigned int* r1 = reinterpret_cast<unsigned int*>(&sP[(j0 + 1) * 72 + c0]);
            r0[0]  = packbf(sx0[0], sx0[1]);
            r0[8]  = packbf(sy0[0], sy0[1]);
            r0[16] = packbf(id0[0], id0[1]);
            r1[0]  = packbf(sx1[0], sx1[1]);
            r1[8]  = packbf(sy1[0], sy1[1]);
            r1[16] = packbf(id1[0], id1[1]);
            if (cg == 1) {   // pre-state alive bits for this strip's 2 px
                sPre[s * 64 + j0]     = (mp0 > 0.1f) ? 1 : 0;
                sPre[s * 64 + j0 + 1] = (mp1 > 0.1f) ? 1 : 0;
            }
        }
        // no barrier: sP rows are wave-private

        // ===== [B] GEMM1 =====
        f32x4 acc1[8];
        #pragma unroll
        for (int n = 0; n < 8; ++n) { acc1[n][0]=0.f; acc1[n][1]=0.f; acc1[n][2]=0.f; acc1[n][3]=0.f; }
        #pragma unroll
        for (int kk = 0; kk < 2; ++kk) {
            const short8v a = *reinterpret_cast<const short8v*>(&sP[(wv * 16 + lr) * 72 + kk * 32 + lg * 8]);
            #pragma unroll
            for (int n = 0; n < 8; ++n)
                acc1[n] = __builtin_amdgcn_mfma_f32_16x16x32_bf16(a, w1f[n][kk], acc1[n], 0, 0, 0);
        }
        #pragma unroll
        for (int r = 0; r < 4; ++r) {
            const int row = wv * 16 + lg * 4 + r;
            uint4 u;
            u.x = packbf(fmaxf(acc1[0][r] + b1v[0], 0.f), fmaxf(acc1[1][r] + b1v[1], 0.f));
            u.y = packbf(fmaxf(acc1[2][r] + b1v[2], 0.f), fmaxf(acc1[3][r] + b1v[3], 0.f));
            u.z = packbf(fmaxf(acc1[4][r] + b1v[4], 0.f), fmaxf(acc1[5][r] + b1v[5], 0.f));
            u.w = packbf(fmaxf(acc1[6][r] + b1v[6], 0.f), fmaxf(acc1[7][r] + b1v[7], 0.f));
            *reinterpret_cast<uint4*>(&sH[row * 136 + lr * 8]) = u;
        }
        // no barrier: sH rows are wave-private

        // ===== [C] GEMM2 + exact-f32 residual =====
        f32x4 acc2; acc2[0]=0.f; acc2[1]=0.f; acc2[2]=0.f; acc2[3]=0.f;
        #pragma unroll
        for (int ksx = 0; ksx < 4; ++ksx) {
            const short8v a2 = *reinterpret_cast<const short8v*>(&sH[(wv * 16 + lr) * 136 + ksx * 32 + lg * 8]);
            acc2 = __builtin_amdgcn_mfma_f32_16x16x32_bf16(a2, w2f[ksx], acc2, 0, 0, 0);
        }
        float xv[4];
        xv[0] = fmaf(acc2[0] + b2v, (float)mi.x, idv.x);
        xv[1] = fmaf(acc2[1] + b2v, (float)mi.y, idv.y);
        xv[2] = fmaf(acc2[2] + b2v, (float)mi.z, idv.z);
        xv[3] = fmaf(acc2[3] + b2v, (float)mi.w, idv.w);
        if (lr == 3) {                       // new alpha -> rolling sA (rows 2s,2s+1)
            const int p0 = pbase + lg * 4;
            const int h2 = p0 >> 5, w2c = p0 & 31;
            float* dst = &sA[(h2 & 7) * 34 + (w2c + 1)];
            dst[0] = xv[0]; dst[1] = xv[1]; dst[2] = xv[2]; dst[3] = xv[3];
        }

        // ===== [D] gate strip s-2 =====
        const int par = s & 1;
        if (s >= 2) do_gate(s - 2, xq[par]);
        xq[par][0] = xv[0]; xq[par][1] = xv[1]; xq[par][2] = xv[2]; xq[par][3] = xv[3];

        // commit prefetched rows into their slots (distinct from rows 2s-1..2s+2)
        if (pf_do) {
            unsigned int* dst = reinterpret_cast<unsigned int*>(
                &sSt[pf_ch * 288 + (pf_row & 7) * 36 + pf_px4 * 4 + 2]);
            dst[0] = packbf(pf.x, pf.y);
            dst[1] = packbf(pf.z, pf.w);
        }

        __syncthreads();   // publishes sA rows 2s,2s+1 + state rows 2s+5,2s+6 + sPre
    }
    // drain the 2-strip gating pipeline
    do_gate(14, xq[0]);
    do_gate(15, xq[1]);
}

extern "C" void kernel_launch(void* const* d_in, const int* in_sizes, int n_in,
                              void* d_out, int out_size, void* d_ws, size_t ws_size,
                              hipStream_t stream) {
    const float* state = (const float*)d_in[0];
    const int*   rmask = (const int*)d_in[1];
    const float* w1    = (const float*)d_in[2];
    const float* b1    = (const float*)d_in[3];
    const float* w2    = (const float*)d_in[4];
    const float* b2    = (const float*)d_in[5];
    float* outp = (float*)d_out;

    const int B = in_sizes[0] / (16 * 32 * 32);   // 1024
    hipLaunchKernelGGL(nca_mfma, dim3(B), dim3(TPB), 0, stream,
                       state, rmask, w1, b1, w2, b2, outp);
}

// Round 9
// 211.351 us; speedup vs baseline: 1.2926x; 1.2926x over previous
//
#include <hip/hip_runtime.h>
#include <hip/hip_bf16.h>

#define TPB 256
#define RS  592   // sSt row stride in shorts (1184 B = 296 u32 -> +8 banks per row)

typedef __attribute__((ext_vector_type(8))) short short8v;   // 8 bf16 MFMA operand
typedef __attribute__((ext_vector_type(4))) float f32x4;     // MFMA accumulator

__device__ __forceinline__ float bf2f(unsigned int u) {
    return __uint_as_float(u << 16);
}
__device__ __forceinline__ unsigned int packbf(float x, float y) {
    unsigned int r;
    asm("v_cvt_pk_bf16_f32 %0, %1, %2" : "=v"(r) : "v"(x), "v"(y));
    return r;
}
__device__ __forceinline__ short8v pack8f(const float* v) {
    union { unsigned int u[4]; short8v s; } c;
    c.u[0] = packbf(v[0], v[1]); c.u[1] = packbf(v[2], v[3]);
    c.u[2] = packbf(v[4], v[5]); c.u[3] = packbf(v[6], v[7]);
    return c.s;
}
__device__ __forceinline__ short8v pack8(float4 a, float4 bq) {
    union { unsigned int u[4]; short8v s; } c;
    c.u[0] = packbf(a.x, a.y);  c.u[1] = packbf(a.z, a.w);
    c.u[2] = packbf(bq.x, bq.y); c.u[3] = packbf(bq.z, bq.w);
    return c.s;
}

// Conv-folded NCA step. One block per image, 4 waves, 16 strips of 64 px.
// GEMM1 is a direct 3x3 conv-GEMM: K = 9 taps x 16 ch (=144, pad 160);
// A-frags = ds_read_b128 of 8 contiguous channels from channel-innermost
// state tile sSt[34][36+pad][16]. Sobel folded into W1 on the fly (K').
// No perception phase, no sP. sH/GEMM2/gating identical to the 104us R5 kernel.
__global__ __launch_bounds__(TPB, 2) void nca_conv(
    const float* __restrict__ state,   // [B,16,32,32]
    const int*   __restrict__ rmask,   // [B,1,32,32]
    const float* __restrict__ w1,      // [128,48]
    const float* __restrict__ b1,      // [128]
    const float* __restrict__ w2,      // [16,128]
    const float* __restrict__ b2,      // [16]
    float* __restrict__ out)           // [B,16,32,32]
{
    __shared__ __align__(16) unsigned short sSt[34 * RS];   // 40256 B, [row][col+2][ch]
    __shared__ __align__(16) unsigned short sH [64 * 136];  // 17408 B, wave-private rows
    __shared__ __align__(16) float          sA [34 * 34];   //  4624 B, new alpha, padded
    __shared__ unsigned char                sPre[1024];     //  1024 B  -> total 63312 B

    const int b    = blockIdx.x;
    const int tid  = threadIdx.x;
    const int lane = tid & 63;
    const int wv   = tid >> 6;
    const int lr   = lane & 15;
    const int lg   = lane >> 4;
    const int lh   = lg >> 1;          // tap parity
    const int c0   = (lg & 1) * 8;     // channel-half

    // Sobel taps, row-major tap = dr*3+dc (correlation, matches lax.conv)
    // SXT: -1 0 1 -2 0 2 -1 0 1 ; SYT: -1 -2 -1 0 0 0 1 2 1

    // -------- conv-folded W1 fragments: K'[f][tap*16+c], k = kk*32+lg*8+e ----
    short8v w1f[8][5];
    short8v w2f[4];
    float   b1v[8];
    {
        const float SXT[10] = {-1.f,0.f,1.f,-2.f,0.f,2.f,-1.f,0.f,1.f,0.f};
        const float SYT[10] = {-1.f,-2.f,-1.f,0.f,0.f,0.f,1.f,2.f,1.f,0.f};
        #pragma unroll
        for (int n = 0; n < 8; ++n) {
            const int f = lr * 8 + n;
            float wx[8], wy[8], ws[8];
            {
                const float4 a0 = *reinterpret_cast<const float4*>(w1 + f*48 + c0);
                const float4 a1 = *reinterpret_cast<const float4*>(w1 + f*48 + c0 + 4);
                const float4 y0 = *reinterpret_cast<const float4*>(w1 + f*48 + 16 + c0);
                const float4 y1 = *reinterpret_cast<const float4*>(w1 + f*48 + 16 + c0 + 4);
                const float4 s0 = *reinterpret_cast<const float4*>(w1 + f*48 + 32 + c0);
                const float4 s1 = *reinterpret_cast<const float4*>(w1 + f*48 + 32 + c0 + 4);
                wx[0]=a0.x; wx[1]=a0.y; wx[2]=a0.z; wx[3]=a0.w; wx[4]=a1.x; wx[5]=a1.y; wx[6]=a1.z; wx[7]=a1.w;
                wy[0]=y0.x; wy[1]=y0.y; wy[2]=y0.z; wy[3]=y0.w; wy[4]=y1.x; wy[5]=y1.y; wy[6]=y1.z; wy[7]=y1.w;
                ws[0]=s0.x; ws[1]=s0.y; ws[2]=s0.z; ws[3]=s0.w; ws[4]=s1.x; ws[5]=s1.y; ws[6]=s1.z; ws[7]=s1.w;
            }
            #pragma unroll
            for (int kk = 0; kk < 5; ++kk) {
                const float sx = lh ? SXT[2*kk+1] : SXT[2*kk];
                const float sy = lh ? SYT[2*kk+1] : SYT[2*kk];
                const float si = (kk == 2 && lh == 0) ? 1.f : 0.f;  // tap 4 identity
                const float kill = (kk == 4 && lh == 1) ? 0.f : 1.f; // tap 9 = K-pad
                float v[8];
                #pragma unroll
                for (int e = 0; e < 8; ++e)
                    v[e] = (wx[e]*sx + wy[e]*sy + ws[e]*si) * kill;
                w1f[n][kk] = pack8f(v);
            }
            b1v[n] = b1[f];
        }
        #pragma unroll
        for (int ks = 0; ks < 4; ++ks) {
            const int k0 = ks * 32 + lg * 8;
            const float4 x0 = *reinterpret_cast<const float4*>(w2 + lr*128 + k0);
            const float4 x1 = *reinterpret_cast<const float4*>(w2 + lr*128 + k0 + 4);
            w2f[ks] = pack8(x0, x1);
        }
    }
    const float b2v = b2[lr];

    // -------- zero sSt (halos) + sA ----------------------------------------
    for (int i = tid; i < 34*RS/2; i += TPB) reinterpret_cast<unsigned int*>(sSt)[i] = 0u;
    for (int i = tid; i < 34*34;   i += TPB) sA[i] = 0.f;
    __syncthreads();

    // -------- stage state -> sSt, transposing to channel-innermost ---------
    // px (h,w) ch c at sSt[(h+1)*RS + (w+2)*16 + c]
    const float* gs = state + (size_t)b * 16384;
    #pragma unroll
    for (int i = 0; i < 8; ++i) {
        const int q4 = tid + i * TPB;        // 0..2047
        const int cpair = q4 >> 8;           // 0..7  (ch 2*cpair, 2*cpair+1)
        const int px4 = q4 & 255;            // float4 index within channel
        const int h = px4 >> 3, w4 = px4 & 7;
        const float4 va = reinterpret_cast<const float4*>(gs)[cpair*512 + px4];
        const float4 vb = reinterpret_cast<const float4*>(gs)[cpair*512 + 256 + px4];
        unsigned int* dst = reinterpret_cast<unsigned int*>(sSt);
        const int base = (h + 1) * (RS/2) + (w4*4 + 2) * 8 + cpair;
        dst[base]      = packbf(va.x, vb.x);
        dst[base + 8]  = packbf(va.y, vb.y);
        dst[base + 16] = packbf(va.z, vb.z);
        dst[base + 24] = packbf(va.w, vb.w);
    }
    __syncthreads();

    // -------- pre-state alive pool (alpha = ch 3) ---------------------------
    for (int p = tid; p < 1024; p += TPB) {
        const int h = p >> 5, w = p & 31;
        float m = 0.f;
        #pragma unroll
        for (int dr = 0; dr < 3; ++dr)
            #pragma unroll
            for (int dc = 0; dc < 3; ++dc)
                m = fmaxf(m, bf2f(sSt[(h+dr)*RS + (w+1+dc)*16 + 3]));
        sPre[p] = (m > 0.1f) ? 1 : 0;
    }

    // A-frag row/col offsets per kk (tap = 2kk+lh), thread-invariant
    int roff[5];
    #pragma unroll
    for (int kk = 0; kk < 5; ++kk) {
        // DR[t]=t/3, DC[t]=t%3 for t=2kk (lh=0) or 2kk+1 (lh=1); t=9 clamped to 8
        const int te = 2*kk, to = (2*kk+1 > 8) ? 8 : 2*kk+1;
        const int re = (te/3)*RS + (te%3)*16;
        const int ro = (to/3)*RS + (to%3)*16;
        roff[kk] = lh ? ro : re;
    }

    auto do_gate = [&](int g, const float* xp) {
        float av = 0.f;
        if (lane < 16) {
            const int p = g * 64 + wv * 16 + lane;
            const int h = p >> 5, w = p & 31;
            const float* sa = &sA[h * 34 + w];
            float m =          sa[0];
            m = fmaxf(m, sa[1]);  m = fmaxf(m, sa[2]);
            m = fmaxf(m, sa[34]); m = fmaxf(m, sa[35]); m = fmaxf(m, sa[36]);
            m = fmaxf(m, sa[68]); m = fmaxf(m, sa[69]); m = fmaxf(m, sa[70]);
            av = ((m > 0.1f) && (sPre[p] != 0)) ? 1.f : 0.f;
        }
        const float g0 = __shfl(av, lg * 4 + 0);
        const float g1 = __shfl(av, lg * 4 + 1);
        const float g2 = __shfl(av, lg * 4 + 2);
        const float g3 = __shfl(av, lg * 4 + 3);
        float4 ov;
        ov.x = g0 * fminf(fmaxf(xp[0], 0.f), 1.f);
        ov.y = g1 * fminf(fmaxf(xp[1], 0.f), 1.f);
        ov.z = g2 * fminf(fmaxf(xp[2], 0.f), 1.f);
        ov.w = g3 * fminf(fmaxf(xp[3], 0.f), 1.f);
        *reinterpret_cast<float4*>(&out[(size_t)b * 16384 + lr * 1024 + g * 64 + wv * 16 + lg * 4]) = ov;
    };

    float xq[2][4];

    for (int s = 0; s < 16; ++s) {
        const int pbase = s * 64 + wv * 16;
        const int4   mi  = *reinterpret_cast<const int4*>(&rmask[b * 1024 + pbase + lg * 4]);
        const float4 idv = *reinterpret_cast<const float4*>(&state[(size_t)b * 16384 + lr * 1024 + pbase + lg * 4]);

        // ===== GEMM1: conv-GEMM, A direct from sSt =====
        const int p = pbase + lr;
        const int h = p >> 5, w = p & 31;
        const unsigned aBase = (unsigned)(h * RS + (w + 1) * 16 + c0);

        short8v afr[5];
        #pragma unroll
        for (int kk = 0; kk < 5; ++kk)
            afr[kk] = *reinterpret_cast<const short8v*>(&sSt[aBase + roff[kk]]);
        if (lh) { short8v z = {0,0,0,0,0,0,0,0}; afr[4] = z; }  // K-pad lanes

        f32x4 acc1[8];
        #pragma unroll
        for (int n = 0; n < 8; ++n) { acc1[n][0]=0.f; acc1[n][1]=0.f; acc1[n][2]=0.f; acc1[n][3]=0.f; }
        #pragma unroll
        for (int kk = 0; kk < 5; ++kk) {
            #pragma unroll
            for (int n = 0; n < 8; ++n)
                acc1[n] = __builtin_amdgcn_mfma_f32_16x16x32_bf16(afr[kk], w1f[n][kk], acc1[n], 0, 0, 0);
        }
        // epilogue: bias+relu -> sH (8 consecutive features per lane)
        #pragma unroll
        for (int r = 0; r < 4; ++r) {
            const int row = wv * 16 + lg * 4 + r;
            uint4 u;
            u.x = packbf(fmaxf(acc1[0][r] + b1v[0], 0.f), fmaxf(acc1[1][r] + b1v[1], 0.f));
            u.y = packbf(fmaxf(acc1[2][r] + b1v[2], 0.f), fmaxf(acc1[3][r] + b1v[3], 0.f));
            u.z = packbf(fmaxf(acc1[4][r] + b1v[4], 0.f), fmaxf(acc1[5][r] + b1v[5], 0.f));
            u.w = packbf(fmaxf(acc1[6][r] + b1v[6], 0.f), fmaxf(acc1[7][r] + b1v[7], 0.f));
            *reinterpret_cast<uint4*>(&sH[row * 136 + lr * 8]) = u;
        }
        // no barrier: sH rows are wave-private

        // ===== GEMM2 + exact-f32 residual =====
        f32x4 acc2; acc2[0]=0.f; acc2[1]=0.f; acc2[2]=0.f; acc2[3]=0.f;
        #pragma unroll
        for (int ksx = 0; ksx < 4; ++ksx) {
            const short8v a2 = *reinterpret_cast<const short8v*>(&sH[(wv * 16 + lr) * 136 + ksx * 32 + lg * 8]);
            acc2 = __builtin_amdgcn_mfma_f32_16x16x32_bf16(a2, w2f[ksx], acc2, 0, 0, 0);
        }
        float xv[4];
        xv[0] = fmaf(acc2[0] + b2v, (float)mi.x, idv.x);
        xv[1] = fmaf(acc2[1] + b2v, (float)mi.y, idv.y);
        xv[2] = fmaf(acc2[2] + b2v, (float)mi.z, idv.z);
        xv[3] = fmaf(acc2[3] + b2v, (float)mi.w, idv.w);
        if (lr == 3) {                      // new alpha -> sA
            const int p0 = pbase + lg * 4;
            const int h2 = p0 >> 5, w2c = p0 & 31;
            float* dst = &sA[(h2 + 1) * 34 + (w2c + 1)];
            dst[0] = xv[0]; dst[1] = xv[1]; dst[2] = xv[2]; dst[3] = xv[3];
        }

        // ===== gate strip s-2 =====
        const int par = s & 1;
        if (s >= 2) do_gate(s - 2, xq[par]);
        xq[par][0] = xv[0]; xq[par][1] = xv[1]; xq[par][2] = xv[2]; xq[par][3] = xv[3];

        __syncthreads();   // publish this strip's sA rows
    }
    do_gate(14, xq[0]);
    do_gate(15, xq[1]);
}

extern "C" void kernel_launch(void* const* d_in, const int* in_sizes, int n_in,
                              void* d_out, int out_size, void* d_ws, size_t ws_size,
                              hipStream_t stream) {
    const float* state = (const float*)d_in[0];
    const int*   rmask = (const int*)d_in[1];
    const float* w1    = (const float*)d_in[2];
    const float* b1    = (const float*)d_in[3];
    const float* w2    = (const float*)d_in[4];
    const float* b2    = (const float*)d_in[5];
    float* outp = (float*)d_out;

    const int B = in_sizes[0] / (16 * 32 * 32);   // 1024
    hipLaunchKernelGGL(nca_conv, dim3(B), dim3(TPB), 0, stream,
                       state, rmask, w1, b1, w2, b2, outp);
}

// Round 10
// 184.238 us; speedup vs baseline: 1.4828x; 1.1472x over previous
//
#include <hip/hip_runtime.h>
#include <hip/hip_bf16.h>

#define TPB 256

typedef __attribute__((ext_vector_type(8))) short short8v;   // 8 bf16 MFMA operand
typedef __attribute__((ext_vector_type(4))) float f32x4;     // MFMA accumulator

__device__ __forceinline__ float bf2f(unsigned int u) {
    return __uint_as_float(u << 16);
}
__device__ __forceinline__ unsigned int packbf(float x, float y) {
    unsigned int r;
    asm("v_cvt_pk_bf16_f32 %0, %1, %2" : "=v"(r) : "v"(x), "v"(y));
    return r;
}
__device__ __forceinline__ short8v pack8(float4 a, float4 bq) {
    union { unsigned int u[4]; short8v s; } c;
    c.u[0] = packbf(a.x, a.y);  c.u[1] = packbf(a.z, a.w);
    c.u[2] = packbf(bq.x, bq.y); c.u[3] = packbf(bq.z, bq.w);
    return c.s;
}

// ============ Kernel A: ungated MLP (R5 structure, ZERO loop barriers) =====
// One block per image, 4 waves, 16 strips of 64 px. sP/sH wave-private,
// sSt read-only after staging -> strip loop has no synchronization at all.
// Writes pre-gate x (f32) to out; gating done by nca_gate afterwards.
__global__ __launch_bounds__(TPB, 2) void nca_mlp(
    const float* __restrict__ state,   // [B,16,32,32]
    const int*   __restrict__ rmask,   // [B,1,32,32]
    const float* __restrict__ w1,      // [128,48]
    const float* __restrict__ b1,      // [128]
    const float* __restrict__ w2,      // [16,128]
    const float* __restrict__ b2,      // [16]
    float* __restrict__ out)           // [B,16,32,32] <- ungated x
{
    __shared__ __align__(16) unsigned short sSt[16 * 34 * 36]; // bf16 state, stride 36, data at [h+1][w+2]
    __shared__ __align__(16) unsigned short sP [64 * 72];      // perception, stride 72; wave-private rows
    __shared__ __align__(16) unsigned short sH [64 * 136];     // hidden bf16, stride 136; wave-private rows

    const int b    = blockIdx.x;
    const int tid  = threadIdx.x;
    const int lane = tid & 63;
    const int wv   = tid >> 6;
    const int lr   = lane & 15;
    const int lg   = lane >> 4;

    // ---------------- weight fragments (registers, 64+16 VGPRs) ------------
    short8v w1f[8][2];
    short8v w2f[4];
    float   b1v[8];
    #pragma unroll
    for (int n = 0; n < 8; ++n) {
        const int f = lr * 8 + n;
        #pragma unroll
        for (int kk = 0; kk < 2; ++kk) {
            const int k0 = kk * 32 + lg * 8;
            if (k0 < 48) {
                const float4 x0 = *reinterpret_cast<const float4*>(w1 + f * 48 + k0);
                const float4 x1 = *reinterpret_cast<const float4*>(w1 + f * 48 + k0 + 4);
                w1f[n][kk] = pack8(x0, x1);
            } else {
                short8v z = {0,0,0,0,0,0,0,0};
                w1f[n][kk] = z;
            }
        }
        b1v[n] = b1[f];
    }
    #pragma unroll
    for (int ks = 0; ks < 4; ++ks) {
        const int k0 = ks * 32 + lg * 8;
        const float4 x0 = *reinterpret_cast<const float4*>(w2 + lr * 128 + k0);
        const float4 x1 = *reinterpret_cast<const float4*>(w2 + lr * 128 + k0 + 4);
        w2f[ks] = pack8(x0, x1);
    }
    const float b2v = b2[lr];

    // ---------------- zero LDS (halos + K-pad) -----------------------------
    for (int i = tid; i < 16*34*36/2; i += TPB) reinterpret_cast<unsigned int*>(sSt)[i] = 0u;
    for (int i = tid; i < 64*72/2;    i += TPB) reinterpret_cast<unsigned int*>(sP)[i]  = 0u;
    __syncthreads();

    // ---------------- stage state -> bf16 LDS (coalesced float4) -----------
    const float* gs = state + (size_t)b * 16384;
    #pragma unroll
    for (int k = 0; k < 16; ++k) {
        const int q = tid + k * TPB;
        const float4 v = reinterpret_cast<const float4*>(gs)[q];
        const int c = q >> 8, rem = q & 255;
        const int h = rem >> 3, wg = rem & 7;
        const int eo = c * 1224 + (h + 1) * 36 + (wg * 4 + 2);
        reinterpret_cast<unsigned int*>(&sSt[eo])[0] = packbf(v.x, v.y);
        reinterpret_cast<unsigned int*>(&sSt[eo])[1] = packbf(v.z, v.w);
    }
    __syncthreads();   // last barrier — strip loop below is sync-free

    for (int s = 0; s < 16; ++s) {
        const int pbase = s * 64 + wv * 16;
        const int4   mi  = *reinterpret_cast<const int4*>(&rmask[b * 1024 + pbase + lg * 4]);
        const float4 idv = *reinterpret_cast<const float4*>(&state[(size_t)b * 16384 + lr * 1024 + pbase + lg * 4]);

        // ===== [A] perception: 2 px x 2 ch per thread -> sP (wave-private) ==
        {
            const int cg = tid & 7;
            const int pp = tid >> 3;
            const int c0 = cg * 2;
            const int hloc = pp >> 4;
            const int h  = s * 2 + hloc;
            const int w0 = (pp & 15) * 2;
            const int j0 = hloc * 32 + w0;
            float sx0[2], sx1[2], sy0[2], sy1[2], id0[2], id1[2];
            #pragma unroll
            for (int ci = 0; ci < 2; ++ci) {
                const unsigned short* bp = &sSt[(c0 + ci) * 1224 + h * 36 + w0];
                float A[3], Bv[3], Cv[3], D[3];
                #pragma unroll
                for (int dr = 0; dr < 3; ++dr) {
                    const unsigned int* rp = reinterpret_cast<const unsigned int*>(bp + dr * 36);
                    const unsigned int u0 = rp[0], u1 = rp[1], u2 = rp[2];
                    A[dr]  = bf2f(u0 >> 16);
                    Bv[dr] = bf2f(u1 & 0xffffu);
                    Cv[dr] = bf2f(u1 >> 16);
                    D[dr]  = bf2f(u2 & 0xffffu);
                }
                const float csa = A[0]  + 2.f * A[1]  + A[2];
                const float csb = Bv[0] + 2.f * Bv[1] + Bv[2];
                const float csc = Cv[0] + 2.f * Cv[1] + Cv[2];
                const float csd = D[0]  + 2.f * D[1]  + D[2];
                sx0[ci] = csc - csa;
                sx1[ci] = csd - csb;
                sy0[ci] = (A[2] + 2.f * Bv[2] + Cv[2]) - (A[0] + 2.f * Bv[0] + Cv[0]);
                sy1[ci] = (Bv[2] + 2.f * Cv[2] + D[2]) - (Bv[0] + 2.f * Cv[0] + D[0]);
                id0[ci] = Bv[1];
                id1[ci] = Cv[1];
            }
            unsigned int* r0 = reinterpret_cast<unsigned int*>(&sP[j0 * 72 + c0]);
            unsigned int* r1 = reinterpret_cast<unsigned int*>(&sP[(j0 + 1) * 72 + c0]);
            r0[0]  = packbf(sx0[0], sx0[1]);
            r0[8]  = packbf(sy0[0], sy0[1]);
            r0[16] = packbf(id0[0], id0[1]);
            r1[0]  = packbf(sx1[0], sx1[1]);
            r1[8]  = packbf(sy1[0], sy1[1]);
            r1[16] = packbf(id1[0], id1[1]);
        }

        // ===== [B] GEMM1 ====================================================
        f32x4 acc1[8];
        #pragma unroll
        for (int n = 0; n < 8; ++n) { acc1[n][0]=0.f; acc1[n][1]=0.f; acc1[n][2]=0.f; acc1[n][3]=0.f; }
        #pragma unroll
        for (int kk = 0; kk < 2; ++kk) {
            const short8v a = *reinterpret_cast<const short8v*>(&sP[(wv * 16 + lr) * 72 + kk * 32 + lg * 8]);
            #pragma unroll
            for (int n = 0; n < 8; ++n)
                acc1[n] = __builtin_amdgcn_mfma_f32_16x16x32_bf16(a, w1f[n][kk], acc1[n], 0, 0, 0);
        }
        #pragma unroll
        for (int r = 0; r < 4; ++r) {
            const int row = wv * 16 + lg * 4 + r;
            uint4 u;
            u.x = packbf(fmaxf(acc1[0][r] + b1v[0], 0.f), fmaxf(acc1[1][r] + b1v[1], 0.f));
            u.y = packbf(fmaxf(acc1[2][r] + b1v[2], 0.f), fmaxf(acc1[3][r] + b1v[3], 0.f));
            u.z = packbf(fmaxf(acc1[4][r] + b1v[4], 0.f), fmaxf(acc1[5][r] + b1v[5], 0.f));
            u.w = packbf(fmaxf(acc1[6][r] + b1v[6], 0.f), fmaxf(acc1[7][r] + b1v[7], 0.f));
            *reinterpret_cast<uint4*>(&sH[row * 136 + lr * 8]) = u;
        }

        // ===== [C] GEMM2 + exact-f32 residual -> ungated x to global ========
        f32x4 acc2; acc2[0]=0.f; acc2[1]=0.f; acc2[2]=0.f; acc2[3]=0.f;
        #pragma unroll
        for (int ksx = 0; ksx < 4; ++ksx) {
            const short8v a2 = *reinterpret_cast<const short8v*>(&sH[(wv * 16 + lr) * 136 + ksx * 32 + lg * 8]);
            acc2 = __builtin_amdgcn_mfma_f32_16x16x32_bf16(a2, w2f[ksx], acc2, 0, 0, 0);
        }
        float4 ov;
        ov.x = fmaf(acc2[0] + b2v, (float)mi.x, idv.x);
        ov.y = fmaf(acc2[1] + b2v, (float)mi.y, idv.y);
        ov.z = fmaf(acc2[2] + b2v, (float)mi.z, idv.z);
        ov.w = fmaf(acc2[3] + b2v, (float)mi.w, idv.w);
        *reinterpret_cast<float4*>(&out[(size_t)b * 16384 + lr * 1024 + pbase + lg * 4]) = ov;
    }
}

// ============ Kernel B: alive gating + clip, in place on out ===============
__global__ __launch_bounds__(256) void nca_gate(
    const float* __restrict__ state,   // [B,16,32,32] (pristine input)
    float* __restrict__ out)           // in: ungated x; out: final
{
    __shared__ float aPre [34 * 34];   // state alpha, padded, f32 (ref-exact)
    __shared__ float aPost[34 * 34];   // x alpha, padded
    const int b = blockIdx.x, t = threadIdx.x;

    for (int i = t; i < 34 * 34; i += 256) { aPre[i] = 0.f; aPost[i] = 0.f; }
    __syncthreads();

    const int h  = t >> 3;
    const int w4 = (t & 7) * 4;
    {
        const float4 sv = reinterpret_cast<const float4*>(state + (size_t)b * 16384 + 3072)[t];
        const float4 xv = reinterpret_cast<const float4*>(out   + (size_t)b * 16384 + 3072)[t];
        float* dp = &aPre [(h + 1) * 34 + w4 + 1];
        float* dq = &aPost[(h + 1) * 34 + w4 + 1];
        dp[0] = sv.x; dp[1] = sv.y; dp[2] = sv.z; dp[3] = sv.w;
        dq[0] = xv.x; dq[1] = xv.y; dq[2] = xv.z; dq[3] = xv.w;
    }
    __syncthreads();   // alpha fully staged before any in-place overwrite

    float g[4];
    #pragma unroll
    for (int k = 0; k < 4; ++k) {
        const int base = h * 34 + w4 + k;    // top-left of padded 3x3
        const float* p = &aPre[base];
        const float* q = &aPost[base];
        float m1 = p[0];
        m1 = fmaxf(m1, p[1]);  m1 = fmaxf(m1, p[2]);
        m1 = fmaxf(m1, p[34]); m1 = fmaxf(m1, p[35]); m1 = fmaxf(m1, p[36]);
        m1 = fmaxf(m1, p[68]); m1 = fmaxf(m1, p[69]); m1 = fmaxf(m1, p[70]);
        float m2 = q[0];
        m2 = fmaxf(m2, q[1]);  m2 = fmaxf(m2, q[2]);
        m2 = fmaxf(m2, q[34]); m2 = fmaxf(m2, q[35]); m2 = fmaxf(m2, q[36]);
        m2 = fmaxf(m2, q[68]); m2 = fmaxf(m2, q[69]); m2 = fmaxf(m2, q[70]);
        g[k] = ((m1 > 0.1f) && (m2 > 0.1f)) ? 1.f : 0.f;
    }

    float* ob = out + (size_t)b * 16384;
    #pragma unroll
    for (int c = 0; c < 16; ++c) {
        float4 v = reinterpret_cast<const float4*>(ob + c * 1024)[t];
        v.x = g[0] * fminf(fmaxf(v.x, 0.f), 1.f);
        v.y = g[1] * fminf(fmaxf(v.y, 0.f), 1.f);
        v.z = g[2] * fminf(fmaxf(v.z, 0.f), 1.f);
        v.w = g[3] * fminf(fmaxf(v.w, 0.f), 1.f);
        reinterpret_cast<float4*>(ob + c * 1024)[t] = v;
    }
}

extern "C" void kernel_launch(void* const* d_in, const int* in_sizes, int n_in,
                              void* d_out, int out_size, void* d_ws, size_t ws_size,
                              hipStream_t stream) {
    const float* state = (const float*)d_in[0];
    const int*   rmask = (const int*)d_in[1];
    const float* w1    = (const float*)d_in[2];
    const float* b1    = (const float*)d_in[3];
    const float* w2    = (const float*)d_in[4];
    const float* b2    = (const float*)d_in[5];
    float* outp = (float*)d_out;

    const int B = in_sizes[0] / (16 * 32 * 32);   // 1024
    hipLaunchKernelGGL(nca_mlp,  dim3(B), dim3(TPB), 0, stream,
                       state, rmask, w1, b1, w2, b2, outp);
    hipLaunchKernelGGL(nca_gate, dim3(B), dim3(256), 0, stream,
                       state, outp);
}